// Round 2
// baseline (360.117 us; speedup 1.0000x reference)
//
#include <hip/hip_runtime.h>

#define DENSE_L 20
#define LT 16
#define RPT 2          // rows per thread
#define BLOCK 256

typedef float v4f __attribute__((ext_vector_type(4)));   // clang-native, OK for nontemporal builtin

// __launch_bounds__(256, 4): min 4 waves/EU forces VGPR <= 128 -> 16 waves/CU
// (was 208 VGPR -> 8 waves/CU, OccupancyPercent 8.3, latency-bound).
__global__ __launch_bounds__(BLOCK, 4) void sampling_kernel(
    const float* __restrict__ x, const float* __restrict__ weight,
    float* __restrict__ out, int nrows)
{
    __shared__ float Gs[DENSE_L * LT];   // layout [t][k]
    const float inv_std2 = 1.0f / (0.4f * 0.4f);   // 6.25

    for (int i = threadIdx.x; i < DENSE_L * LT; i += BLOCK) {
        int t = i >> 4;       // i / 16
        int k = i & 15;       // i % 16
        float d = (float)(t + 1) - weight[k];
        Gs[i] = __expf(-d * d * inv_std2);
    }
    __syncthreads();

    int base = blockIdx.x * (BLOCK * RPT) + threadIdx.x;

    // load x rows: 5 float4 per row, fully unrolled (10 loads in flight)
    float xv0[DENSE_L], xv1[DENSE_L];
    int row0 = base;
    int row1 = base + BLOCK;
    bool v0 = (row0 < nrows), v1 = (row1 < nrows);

    if (v0) {
        const float4* p = reinterpret_cast<const float4*>(x + (size_t)row0 * DENSE_L);
        #pragma unroll
        for (int j = 0; j < DENSE_L / 4; ++j) {
            float4 v = p[j];
            xv0[4*j+0] = v.x; xv0[4*j+1] = v.y; xv0[4*j+2] = v.z; xv0[4*j+3] = v.w;
        }
    }
    if (v1) {
        const float4* p = reinterpret_cast<const float4*>(x + (size_t)row1 * DENSE_L);
        #pragma unroll
        for (int j = 0; j < DENSE_L / 4; ++j) {
            float4 v = p[j];
            xv1[4*j+0] = v.x; xv1[4*j+1] = v.y; xv1[4*j+2] = v.z; xv1[4*j+3] = v.w;
        }
    }

    float a0[LT], a1[LT];
    #pragma unroll
    for (int k = 0; k < LT; ++k) { a0[k] = 0.f; a1[k] = 0.f; }

    #pragma unroll
    for (int t = 0; t < DENSE_L; ++t) {
        const float4* gp = reinterpret_cast<const float4*>(Gs + t * LT);
        float4 g0 = gp[0], g1 = gp[1], g2 = gp[2], g3 = gp[3];
        float xt0 = xv0[t];
        a0[ 0] += xt0 * g0.x; a0[ 1] += xt0 * g0.y; a0[ 2] += xt0 * g0.z; a0[ 3] += xt0 * g0.w;
        a0[ 4] += xt0 * g1.x; a0[ 5] += xt0 * g1.y; a0[ 6] += xt0 * g1.z; a0[ 7] += xt0 * g1.w;
        a0[ 8] += xt0 * g2.x; a0[ 9] += xt0 * g2.y; a0[10] += xt0 * g2.z; a0[11] += xt0 * g2.w;
        a0[12] += xt0 * g3.x; a0[13] += xt0 * g3.y; a0[14] += xt0 * g3.z; a0[15] += xt0 * g3.w;
        float xt1 = xv1[t];
        a1[ 0] += xt1 * g0.x; a1[ 1] += xt1 * g0.y; a1[ 2] += xt1 * g0.z; a1[ 3] += xt1 * g0.w;
        a1[ 4] += xt1 * g1.x; a1[ 5] += xt1 * g1.y; a1[ 6] += xt1 * g1.z; a1[ 7] += xt1 * g1.w;
        a1[ 8] += xt1 * g2.x; a1[ 9] += xt1 * g2.y; a1[10] += xt1 * g2.z; a1[11] += xt1 * g2.w;
        a1[12] += xt1 * g3.x; a1[13] += xt1 * g3.y; a1[14] += xt1 * g3.z; a1[15] += xt1 * g3.w;
    }

    // out is streamed, never re-read: non-temporal stores keep L2 for x.
    if (v0) {
        v4f* o = reinterpret_cast<v4f*>(out + (size_t)row0 * LT);
        __builtin_nontemporal_store((v4f){a0[0], a0[1], a0[2], a0[3]},     o + 0);
        __builtin_nontemporal_store((v4f){a0[4], a0[5], a0[6], a0[7]},     o + 1);
        __builtin_nontemporal_store((v4f){a0[8], a0[9], a0[10], a0[11]},   o + 2);
        __builtin_nontemporal_store((v4f){a0[12], a0[13], a0[14], a0[15]}, o + 3);
    }
    if (v1) {
        v4f* o = reinterpret_cast<v4f*>(out + (size_t)row1 * LT);
        __builtin_nontemporal_store((v4f){a1[0], a1[1], a1[2], a1[3]},     o + 0);
        __builtin_nontemporal_store((v4f){a1[4], a1[5], a1[6], a1[7]},     o + 1);
        __builtin_nontemporal_store((v4f){a1[8], a1[9], a1[10], a1[11]},   o + 2);
        __builtin_nontemporal_store((v4f){a1[12], a1[13], a1[14], a1[15]}, o + 3);
    }
}

extern "C" void kernel_launch(void* const* d_in, const int* in_sizes, int n_in,
                              void* d_out, int out_size, void* d_ws, size_t ws_size,
                              hipStream_t stream) {
    const float* x = (const float*)d_in[0];
    const float* w = (const float*)d_in[1];
    float* out = (float*)d_out;
    int nrows = in_sizes[0] / DENSE_L;   // 1,048,576
    int grid = (nrows + BLOCK * RPT - 1) / (BLOCK * RPT);
    sampling_kernel<<<grid, BLOCK, 0, stream>>>(x, w, out, nrows);
}

// Round 3
// 181.615 us; speedup vs baseline: 1.9829x; 1.9829x over previous
//
#include <hip/hip_runtime.h>

#define DENSE_L 20
#define LT 16
#define RPT 2          // rows per thread
#define BLOCK 256

typedef float v4f __attribute__((ext_vector_type(4)));   // clang-native, OK for nontemporal builtin

// Round-2 lesson: (256,4) forced VGPR=64 -> mass spill (FETCH 41->581 MB, 378 us).
// Fix: k-split halves the accumulator live set (~90 live), cap gently at (256,3)
// (~168 VGPR bound). Expect ~96-140 VGPR, no spill, 3-4 waves/SIMD vs baseline 2.
__global__ __launch_bounds__(BLOCK, 3) void sampling_kernel(
    const float* __restrict__ x, const float* __restrict__ weight,
    float* __restrict__ out, int nrows)
{
    __shared__ float Gs[DENSE_L * LT];   // layout [t][k]
    const float inv_std2 = 1.0f / (0.4f * 0.4f);   // 6.25

    for (int i = threadIdx.x; i < DENSE_L * LT; i += BLOCK) {
        int t = i >> 4;       // i / 16
        int k = i & 15;       // i % 16
        float d = (float)(t + 1) - weight[k];
        Gs[i] = __expf(-d * d * inv_std2);
    }
    __syncthreads();

    int base = blockIdx.x * (BLOCK * RPT) + threadIdx.x;

    int row0 = base;
    int row1 = base + BLOCK;
    bool v0 = (row0 < nrows), v1 = (row1 < nrows);

    // x rows register-resident across both k-halves: 10 float4 loads in flight.
    float xv0[DENSE_L], xv1[DENSE_L];
    if (v0) {
        const float4* p = reinterpret_cast<const float4*>(x + (size_t)row0 * DENSE_L);
        #pragma unroll
        for (int j = 0; j < DENSE_L / 4; ++j) {
            float4 v = p[j];
            xv0[4*j+0] = v.x; xv0[4*j+1] = v.y; xv0[4*j+2] = v.z; xv0[4*j+3] = v.w;
        }
    }
    if (v1) {
        const float4* p = reinterpret_cast<const float4*>(x + (size_t)row1 * DENSE_L);
        #pragma unroll
        for (int j = 0; j < DENSE_L / 4; ++j) {
            float4 v = p[j];
            xv1[4*j+0] = v.x; xv1[4*j+1] = v.y; xv1[4*j+2] = v.z; xv1[4*j+3] = v.w;
        }
    }

    // ---- k-half 0: outputs 0..7 (acc live = 16 floats, not 32) ----
    {
        float a0[8], a1[8];
        #pragma unroll
        for (int k = 0; k < 8; ++k) { a0[k] = 0.f; a1[k] = 0.f; }

        #pragma unroll
        for (int t = 0; t < DENSE_L; ++t) {
            const v4f* gp = reinterpret_cast<const v4f*>(Gs + t * LT);
            v4f g0 = gp[0], g1 = gp[1];
            float xt0 = xv0[t];
            a0[0] += xt0 * g0.x; a0[1] += xt0 * g0.y; a0[2] += xt0 * g0.z; a0[3] += xt0 * g0.w;
            a0[4] += xt0 * g1.x; a0[5] += xt0 * g1.y; a0[6] += xt0 * g1.z; a0[7] += xt0 * g1.w;
            float xt1 = xv1[t];
            a1[0] += xt1 * g0.x; a1[1] += xt1 * g0.y; a1[2] += xt1 * g0.z; a1[3] += xt1 * g0.w;
            a1[4] += xt1 * g1.x; a1[5] += xt1 * g1.y; a1[6] += xt1 * g1.z; a1[7] += xt1 * g1.w;
        }

        if (v0) {
            v4f* o = reinterpret_cast<v4f*>(out + (size_t)row0 * LT);
            __builtin_nontemporal_store((v4f){a0[0], a0[1], a0[2], a0[3]}, o + 0);
            __builtin_nontemporal_store((v4f){a0[4], a0[5], a0[6], a0[7]}, o + 1);
        }
        if (v1) {
            v4f* o = reinterpret_cast<v4f*>(out + (size_t)row1 * LT);
            __builtin_nontemporal_store((v4f){a1[0], a1[1], a1[2], a1[3]}, o + 0);
            __builtin_nontemporal_store((v4f){a1[4], a1[5], a1[6], a1[7]}, o + 1);
        }
    }

    // ---- k-half 1: outputs 8..15 ----
    {
        float a0[8], a1[8];
        #pragma unroll
        for (int k = 0; k < 8; ++k) { a0[k] = 0.f; a1[k] = 0.f; }

        #pragma unroll
        for (int t = 0; t < DENSE_L; ++t) {
            const v4f* gp = reinterpret_cast<const v4f*>(Gs + t * LT + 8);
            v4f g2 = gp[0], g3 = gp[1];
            float xt0 = xv0[t];
            a0[0] += xt0 * g2.x; a0[1] += xt0 * g2.y; a0[2] += xt0 * g2.z; a0[3] += xt0 * g2.w;
            a0[4] += xt0 * g3.x; a0[5] += xt0 * g3.y; a0[6] += xt0 * g3.z; a0[7] += xt0 * g3.w;
            float xt1 = xv1[t];
            a1[0] += xt1 * g2.x; a1[1] += xt1 * g2.y; a1[2] += xt1 * g2.z; a1[3] += xt1 * g2.w;
            a1[4] += xt1 * g3.x; a1[5] += xt1 * g3.y; a1[6] += xt1 * g3.z; a1[7] += xt1 * g3.w;
        }

        if (v0) {
            v4f* o = reinterpret_cast<v4f*>(out + (size_t)row0 * LT);
            __builtin_nontemporal_store((v4f){a0[0], a0[1], a0[2], a0[3]}, o + 2);
            __builtin_nontemporal_store((v4f){a0[4], a0[5], a0[6], a0[7]}, o + 3);
        }
        if (v1) {
            v4f* o = reinterpret_cast<v4f*>(out + (size_t)row1 * LT);
            __builtin_nontemporal_store((v4f){a1[0], a1[1], a1[2], a1[3]}, o + 2);
            __builtin_nontemporal_store((v4f){a1[4], a1[5], a1[6], a1[7]}, o + 3);
        }
    }
}

extern "C" void kernel_launch(void* const* d_in, const int* in_sizes, int n_in,
                              void* d_out, int out_size, void* d_ws, size_t ws_size,
                              hipStream_t stream) {
    const float* x = (const float*)d_in[0];
    const float* w = (const float*)d_in[1];
    float* out = (float*)d_out;
    int nrows = in_sizes[0] / DENSE_L;   // 1,048,576
    int grid = (nrows + BLOCK * RPT - 1) / (BLOCK * RPT);
    sampling_kernel<<<grid, BLOCK, 0, stream>>>(x, w, out, nrows);
}

// Round 4
// 62.778 us; speedup vs baseline: 5.7364x; 2.8930x over previous
//
#include <hip/hip_runtime.h>

#define DENSE_L 20
#define LT 16
#define RPT 2          // rows per thread
#define BLOCK 256
#define TCHUNK 4       // t-values per streamed chunk (one float4 of x per row)
#define NCHUNK (DENSE_L / TCHUNK)   // 5

typedef float v4f __attribute__((ext_vector_type(4)));

// R2/R3 lesson: __launch_bounds__ min-waves makes the allocator overshoot
// occupancy and spill (84 VGPR + 570MB scratch traffic). Instead: streaming
// t-chunk structure so the NATURAL live set is ~75 regs (acc 32 + x 16 + G 16),
// no min-waves hint. #pragma unroll 1 prevents re-hoisting all x loads.
__global__ __launch_bounds__(BLOCK) void sampling_kernel(
    const float* __restrict__ x, const float* __restrict__ weight,
    float* __restrict__ out, int nrows)
{
    __shared__ float Gs[DENSE_L * LT];   // layout [t][k]
    const float inv_std2 = 1.0f / (0.4f * 0.4f);   // 6.25

    for (int i = threadIdx.x; i < DENSE_L * LT; i += BLOCK) {
        int t = i >> 4;       // i / 16
        int k = i & 15;       // i % 16
        float d = (float)(t + 1) - weight[k];
        Gs[i] = __expf(-d * d * inv_std2);
    }
    __syncthreads();

    int row0 = blockIdx.x * (BLOCK * RPT) + threadIdx.x;
    int row1 = row0 + BLOCK;
    bool v0 = (row0 < nrows), v1 = (row1 < nrows);
    // clamped rows make loads always-safe without per-iteration predication
    int r0c = v0 ? row0 : (nrows - 1);
    int r1c = v1 ? row1 : (nrows - 1);

    const float4* p0 = reinterpret_cast<const float4*>(x + (size_t)r0c * DENSE_L);
    const float4* p1 = reinterpret_cast<const float4*>(x + (size_t)r1c * DENSE_L);

    float a0[LT], a1[LT];
    #pragma unroll
    for (int k = 0; k < LT; ++k) { a0[k] = 0.f; a1[k] = 0.f; }

    // 1-deep prefetch pipeline over 5 chunks
    float4 xa = p0[0];
    float4 xb = p1[0];

    #pragma unroll 1
    for (int c = 0; c < NCHUNK; ++c) {
        int cn = (c + 1 < NCHUNK) ? c + 1 : NCHUNK - 1;   // clamped (redundant last load hits L1)
        float4 na = p0[cn];
        float4 nb = p1[cn];

        const float* gbase = Gs + c * (TCHUNK * LT);
        float xs0[TCHUNK] = {xa.x, xa.y, xa.z, xa.w};
        float xs1[TCHUNK] = {xb.x, xb.y, xb.z, xb.w};

        #pragma unroll
        for (int tt = 0; tt < TCHUNK; ++tt) {
            const v4f* gp = reinterpret_cast<const v4f*>(gbase + tt * LT);
            v4f g0 = gp[0], g1 = gp[1], g2 = gp[2], g3 = gp[3];
            float xt0 = xs0[tt];
            a0[ 0] += xt0 * g0.x; a0[ 1] += xt0 * g0.y; a0[ 2] += xt0 * g0.z; a0[ 3] += xt0 * g0.w;
            a0[ 4] += xt0 * g1.x; a0[ 5] += xt0 * g1.y; a0[ 6] += xt0 * g1.z; a0[ 7] += xt0 * g1.w;
            a0[ 8] += xt0 * g2.x; a0[ 9] += xt0 * g2.y; a0[10] += xt0 * g2.z; a0[11] += xt0 * g2.w;
            a0[12] += xt0 * g3.x; a0[13] += xt0 * g3.y; a0[14] += xt0 * g3.z; a0[15] += xt0 * g3.w;
            float xt1 = xs1[tt];
            a1[ 0] += xt1 * g0.x; a1[ 1] += xt1 * g0.y; a1[ 2] += xt1 * g0.z; a1[ 3] += xt1 * g0.w;
            a1[ 4] += xt1 * g1.x; a1[ 5] += xt1 * g1.y; a1[ 6] += xt1 * g1.z; a1[ 7] += xt1 * g1.w;
            a1[ 8] += xt1 * g2.x; a1[ 9] += xt1 * g2.y; a1[10] += xt1 * g2.z; a1[11] += xt1 * g2.w;
            a1[12] += xt1 * g3.x; a1[13] += xt1 * g3.y; a1[14] += xt1 * g3.z; a1[15] += xt1 * g3.w;
        }
        xa = na;
        xb = nb;
    }

    // out is streamed, never re-read: non-temporal stores keep L2/L3 for x.
    if (v0) {
        v4f* o = reinterpret_cast<v4f*>(out + (size_t)row0 * LT);
        __builtin_nontemporal_store((v4f){a0[0], a0[1], a0[2], a0[3]},     o + 0);
        __builtin_nontemporal_store((v4f){a0[4], a0[5], a0[6], a0[7]},     o + 1);
        __builtin_nontemporal_store((v4f){a0[8], a0[9], a0[10], a0[11]},   o + 2);
        __builtin_nontemporal_store((v4f){a0[12], a0[13], a0[14], a0[15]}, o + 3);
    }
    if (v1) {
        v4f* o = reinterpret_cast<v4f*>(out + (size_t)row1 * LT);
        __builtin_nontemporal_store((v4f){a1[0], a1[1], a1[2], a1[3]},     o + 0);
        __builtin_nontemporal_store((v4f){a1[4], a1[5], a1[6], a1[7]},     o + 1);
        __builtin_nontemporal_store((v4f){a1[8], a1[9], a1[10], a1[11]},   o + 2);
        __builtin_nontemporal_store((v4f){a1[12], a1[13], a1[14], a1[15]}, o + 3);
    }
}

extern "C" void kernel_launch(void* const* d_in, const int* in_sizes, int n_in,
                              void* d_out, int out_size, void* d_ws, size_t ws_size,
                              hipStream_t stream) {
    const float* x = (const float*)d_in[0];
    const float* w = (const float*)d_in[1];
    float* out = (float*)d_out;
    int nrows = in_sizes[0] / DENSE_L;   // 1,048,576
    int grid = (nrows + BLOCK * RPT - 1) / (BLOCK * RPT);
    sampling_kernel<<<grid, BLOCK, 0, stream>>>(x, w, out, nrows);
}